// Round 3
// baseline (85.586 us; speedup 1.0000x reference)
//
#include <hip/hip_runtime.h>

#define QDIM 21
#define NDIM 1368
#define OUTSTRIDE 64000

typedef __attribute__((ext_vector_type(4))) float f32x4;
typedef __attribute__((ext_vector_type(8))) short bf16x8s;

static __device__ __forceinline__ unsigned short f2bf(float f) {
    unsigned int u = __float_as_uint(f);
    return (unsigned short)((u + 0x7FFFu + ((u >> 16) & 1u)) >> 16);
}

static __device__ __forceinline__ bf16x8s cvt8(const float* s) {
    bf16x8s r;
    #pragma unroll
    for (int i = 0; i < 8; ++i) r[i] = (short)f2bf(s[i]);
    return r;
}

// One 4-wave block computes C[0:64, n0:n0+64] for window position p; each wave
// owns a 32x32 quadrant, fully independent (no LDS, no barriers).
// Fragments are loaded DIRECTLY global->reg: for 16x16x32 MFMA, lane l needs
// 8 consecutive k-elements (k = (l>>4)*8 + 32*t), which never cross a
// q-boundary (8 | k-offset, 8 | w), i.e. 8 contiguous f32 in both x and W.
template<int WLOG2, int NTX, int D, int P, int S, int K>
__device__ __forceinline__ void fbk_body(const float* __restrict__ x,
                                         const float* __restrict__ W,
                                         float* __restrict__ out, int bid) {
    constexpr int WWIN = 1 << WLOG2;
    constexpr int G = (K + 31) / 32;          // number of k-steps of 32
    constexpr bool TAIL = (K % 32) != 0;      // only fb0 (K=336)
    // A-pointer advance (floats) per k-step; for w=64, j alternates +-32 so
    // even->odd and odd->even advances differ.
    constexpr int ADV_EO = (WLOG2 == 6) ? 32 : ((32 >> WLOG2) * NDIM);
    constexpr int ADV_OE = (WLOG2 == 6) ? (NDIM - 32) : ((32 >> WLOG2) * NDIM);

    const int n0 = (bid % NTX) * 64;
    const int p  = bid / NTX;
    const int start = (p == P - 1) ? (NDIM - WWIN) : p * S;

    const int tid  = threadIdx.x;
    const int wid  = tid >> 6;
    const int lane = tid & 63;
    const int wm = (wid >> 1) * 32;   // wave's M offset (batch rows)
    const int wn = (wid & 1) * 32;    // wave's N offset (dd)
    const int lr = lane & 15;
    const int kb = (lane >> 4) * 8;   // k sub-offset within a 32-step

    const int q0 = kb >> WLOG2;
    const int j0 = kb & (WWIN - 1);

    const float* pA0 = x + ((size_t)(wm + lr) * QDIM + q0) * NDIM + start + j0;
    const float* pA1 = pA0 + (size_t)16 * QDIM * NDIM;
    const float* pB0 = W + (size_t)(p * D + n0 + wn + lr) * K + kb;
    const float* pB1 = pB0 + (size_t)16 * K;

    int fg = kb;  // per-lane k index of next group (TAIL predicate only)

    float a0A[8], a1A[8], b0A[8], b1A[8];
    float a0B[8], a1B[8], b0B[8], b1B[8];
    f32x4 acc[2][2] = {};

#define ISSUE(SET, ADV)                                                      \
    {                                                                        \
        bool v_ = true;                                                      \
        if constexpr (TAIL) v_ = (fg < K);                                   \
        if (v_) {                                                            \
            *(float4*)&a0##SET[0] = *(const float4*)(pA0);                   \
            *(float4*)&a0##SET[4] = *(const float4*)(pA0 + 4);               \
            *(float4*)&a1##SET[0] = *(const float4*)(pA1);                   \
            *(float4*)&a1##SET[4] = *(const float4*)(pA1 + 4);               \
            *(float4*)&b0##SET[0] = *(const float4*)(pB0);                   \
            *(float4*)&b0##SET[4] = *(const float4*)(pB0 + 4);               \
            *(float4*)&b1##SET[0] = *(const float4*)(pB1);                   \
            *(float4*)&b1##SET[4] = *(const float4*)(pB1 + 4);               \
        } else {                                                             \
            _Pragma("unroll")                                                \
            for (int z_ = 0; z_ < 8; ++z_) {                                 \
                a0##SET[z_] = 0.f; a1##SET[z_] = 0.f;                        \
                b0##SET[z_] = 0.f; b1##SET[z_] = 0.f;                        \
            }                                                                \
        }                                                                    \
        pA0 += (ADV); pA1 += (ADV); pB0 += 32; pB1 += 32;                    \
        if constexpr (TAIL) fg += 32;                                        \
    }

#define COMPUTE(SET)                                                         \
    {                                                                        \
        bf16x8s A0_ = cvt8(a0##SET), A1_ = cvt8(a1##SET);                    \
        bf16x8s B0_ = cvt8(b0##SET), B1_ = cvt8(b1##SET);                    \
        acc[0][0] = __builtin_amdgcn_mfma_f32_16x16x32_bf16(A0_, B0_, acc[0][0], 0, 0, 0); \
        acc[0][1] = __builtin_amdgcn_mfma_f32_16x16x32_bf16(A0_, B1_, acc[0][1], 0, 0, 0); \
        acc[1][0] = __builtin_amdgcn_mfma_f32_16x16x32_bf16(A1_, B0_, acc[1][0], 0, 0, 0); \
        acc[1][1] = __builtin_amdgcn_mfma_f32_16x16x32_bf16(A1_, B1_, acc[1][1], 0, 0, 0); \
    }

    // 2-deep named register double-buffer: issue k-step g+1 while computing g.
    ISSUE(A, ADV_EO);
    int g = 0;
    #pragma unroll 1
    for (; g + 2 < G; g += 2) {
        ISSUE(B, ADV_OE);
        COMPUTE(A);
        ISSUE(A, ADV_EO);
        COMPUTE(B);
    }
    if (g + 1 < G) {
        ISSUE(B, ADV_OE);
        COMPUTE(A);
        COMPUTE(B);
    } else {
        COMPUTE(A);
    }

#undef ISSUE
#undef COMPUTE

    // epilogue: C/D layout col = lane&15, row = (lane>>4)*4 + r
    const int colbase = p * D + n0;
    #pragma unroll
    for (int mi = 0; mi < 2; ++mi) {
        #pragma unroll
        for (int ni = 0; ni < 2; ++ni) {
            int col = colbase + wn + ni * 16 + lr;
            int rbase = wm + mi * 16 + (lane >> 4) * 4;
            #pragma unroll
            for (int r = 0; r < 4; ++r) {
                out[(size_t)(rbase + r) * OUTSTRIDE + col] = acc[mi][ni][r];
            }
        }
    }
}

// Fused dispatch: 1000 blocks, longest (fb2, 42 k-steps) first.
__global__ __launch_bounds__(256, 4)
void fbk_fused(const float* __restrict__ x,  const float* __restrict__ w0,
               const float* __restrict__ w1, const float* __restrict__ w2,
               float* __restrict__ out) {
    const int bid = blockIdx.x;
    if (bid < 328) {
        // fb2: w=64, s=16, d=256, P=82, K=1344, 4 n-tiles
        fbk_body<6, 4, 256, 82, 16, 1344>(x, w2, out + 43008, bid);
    } else if (bid < 662) {
        // fb1: w=32, s=8, d=128, P=167, K=672, 2 n-tiles
        fbk_body<5, 2, 128, 167, 8, 672>(x, w1, out + 21632, bid - 328);
    } else {
        // fb0: w=16, s=4, d=64, P=338, K=336, 1 n-tile
        fbk_body<4, 1, 64, 338, 4, 336>(x, w0, out, bid - 662);
    }
}

extern "C" void kernel_launch(void* const* d_in, const int* in_sizes, int n_in,
                              void* d_out, int out_size, void* d_ws, size_t ws_size,
                              hipStream_t stream) {
    const float* x  = (const float*)d_in[0];
    const float* w0 = (const float*)d_in[1];
    const float* w1 = (const float*)d_in[2];
    const float* w2 = (const float*)d_in[3];
    float* out = (float*)d_out;
    fbk_fused<<<dim3(1000), 256, 0, stream>>>(x, w0, w1, w2, out);
}

// Round 4
// 55.603 us; speedup vs baseline: 1.5392x; 1.5392x over previous
//
#include <hip/hip_runtime.h>

#define QDIM 21
#define NDIM 1368
#define OUTSTRIDE 64000

typedef __attribute__((ext_vector_type(4))) float f32x4;
typedef __attribute__((ext_vector_type(8))) short bf16x8s;
typedef __attribute__((ext_vector_type(8))) unsigned short u16x8;

static __device__ __forceinline__ unsigned short f2bf(float f) {
    unsigned int u = __float_as_uint(f);
    return (unsigned short)((u + 0x7FFFu + ((u >> 16) & 1u)) >> 16);
}

static __device__ __forceinline__ u16x8 cvt8f(float4 a, float4 b) {
    u16x8 r;
    r[0] = f2bf(a.x); r[1] = f2bf(a.y); r[2] = f2bf(a.z); r[3] = f2bf(a.w);
    r[4] = f2bf(b.x); r[5] = f2bf(b.y); r[6] = f2bf(b.z); r[7] = f2bf(b.w);
    return r;
}

// One 4-wave block computes C[0:64, n0:n0+64] for window position p.
// LDS double-buffered (1 barrier per 64-K tile), 2-tile register prefetch:
//   iter g: issue loads(g+2) -> sA | MFMA tile g from lds[0] | cvt+write sB(g+1)->lds[1] | bar
//           issue loads(g+3) -> sB | MFMA tile g+1 from lds[1] | cvt+write sA(g+2)->lds[0] | bar
template<int WLOG2, int NTX, int D, int P, int S, int K>
__device__ __forceinline__ void fbk_body(const float* __restrict__ x,
                                         const float* __restrict__ W,
                                         float* __restrict__ out, int bid,
                                         unsigned short (*As)[64][72],
                                         unsigned short (*Bs)[64][72]) {
    constexpr int WWIN = 1 << WLOG2;
    constexpr int G64 = (K + 63) / 64;     // 64-wide K tiles: fb2=21, fb1=11, fb0=6

    const int n0 = (bid % NTX) * 64;
    const int p  = bid / NTX;
    const int start = (p == P - 1) ? (NDIM - WWIN) : p * S;

    const int tid  = threadIdx.x;
    const int wid  = tid >> 6;
    const int lane = tid & 63;
    const int wm = (wid >> 1) * 32;
    const int wn = (wid & 1) * 32;
    const int lr = lane & 15;
    const int kb = (lane >> 4) * 8;

    const float* Wp = W + (size_t)(p * D + n0) * K;

    // per-thread staging coords: 2 segments of 8 consecutive k-floats
    int srow[2], scol[2];
    #pragma unroll
    for (int i = 0; i < 2; ++i) {
        int idx = tid + i * 256;           // 0..511
        srow[i] = idx >> 3;                // 0..63
        scol[i] = (idx & 7) * 8;           // 0..56 step 8 (never crosses q-boundary)
    }

    struct Stage { float4 a[2][2]; float4 b[2][2]; };
    Stage sA, sB;                          // two named sets -> static indexing

    auto LOADR = [&](Stage& Sg, int t) {
        #pragma unroll
        for (int i = 0; i < 2; ++i) {
            int f = t * 64 + scol[i];
            if ((K % 64 == 0) || f < K) {  // constexpr-true for fb2 (dominant)
                int q = f >> WLOG2;
                int j = f & (WWIN - 1);
                const float* pa = x + ((size_t)srow[i] * QDIM + q) * NDIM + start + j;
                const float* pb = Wp + (size_t)srow[i] * K + f;
                Sg.a[i][0] = *(const float4*)pa;
                Sg.a[i][1] = *(const float4*)(pa + 4);
                Sg.b[i][0] = *(const float4*)pb;
                Sg.b[i][1] = *(const float4*)(pb + 4);
            } else {
                Sg.a[i][0] = Sg.a[i][1] = make_float4(0.f, 0.f, 0.f, 0.f);
                Sg.b[i][0] = Sg.b[i][1] = make_float4(0.f, 0.f, 0.f, 0.f);
            }
        }
        // pin the issue point: don't let the scheduler sink these loads
        __builtin_amdgcn_sched_barrier(0);
    };

    auto WRITEL = [&](int buf, const Stage& Sg) {
        #pragma unroll
        for (int i = 0; i < 2; ++i) {
            *(u16x8*)(&As[buf][srow[i]][scol[i]]) = cvt8f(Sg.a[i][0], Sg.a[i][1]);
            *(u16x8*)(&Bs[buf][srow[i]][scol[i]]) = cvt8f(Sg.b[i][0], Sg.b[i][1]);
        }
    };

    f32x4 acc[2][2] = {};
    auto COMPUTE = [&](int buf) {
        #pragma unroll
        for (int kk = 0; kk < 2; ++kk) {
            int ko = kk * 32 + kb;
            bf16x8s a0 = *(const bf16x8s*)(&As[buf][wm + lr][ko]);
            bf16x8s a1 = *(const bf16x8s*)(&As[buf][wm + 16 + lr][ko]);
            bf16x8s b0 = *(const bf16x8s*)(&Bs[buf][wn + lr][ko]);
            bf16x8s b1 = *(const bf16x8s*)(&Bs[buf][wn + 16 + lr][ko]);
            acc[0][0] = __builtin_amdgcn_mfma_f32_16x16x32_bf16(a0, b0, acc[0][0], 0, 0, 0);
            acc[0][1] = __builtin_amdgcn_mfma_f32_16x16x32_bf16(a0, b1, acc[0][1], 0, 0, 0);
            acc[1][0] = __builtin_amdgcn_mfma_f32_16x16x32_bf16(a1, b0, acc[1][0], 0, 0, 0);
            acc[1][1] = __builtin_amdgcn_mfma_f32_16x16x32_bf16(a1, b1, acc[1][1], 0, 0, 0);
        }
    };

    // prologue: tile0 -> sA -> lds[0]; tile1 -> sB (stays in regs)
    LOADR(sA, 0);
    LOADR(sB, 1);
    WRITEL(0, sA);
    __syncthreads();

    #pragma unroll 1
    for (int g = 0; g + 2 < G64; g += 2) {
        LOADR(sA, g + 2);
        COMPUTE(0);            // tile g
        WRITEL(1, sB);         // tile g+1 -> lds[1]  (counted vmcnt: 8 newer loads in flight)
        __syncthreads();
        if (g + 3 < G64) LOADR(sB, g + 3);
        COMPUTE(1);            // tile g+1
        WRITEL(0, sA);         // tile g+2 -> lds[0]
        __syncthreads();
    }
    if constexpr ((G64 & 1) == 0) {
        COMPUTE(0);            // tile G64-2
        WRITEL(1, sB);         // tile G64-1
        __syncthreads();
        COMPUTE(1);            // tile G64-1
    } else {
        COMPUTE(0);            // tile G64-1 (even index -> lds[0])
    }

    // epilogue: C/D layout col = lane&15, row = (lane>>4)*4 + r
    const int colbase = p * D + n0;
    #pragma unroll
    for (int mi = 0; mi < 2; ++mi) {
        #pragma unroll
        for (int ni = 0; ni < 2; ++ni) {
            int col = colbase + wn + ni * 16 + lr;
            int rbase = wm + mi * 16 + (lane >> 4) * 4;
            #pragma unroll
            for (int r = 0; r < 4; ++r) {
                out[(size_t)(rbase + r) * OUTSTRIDE + col] = acc[mi][ni][r];
            }
        }
    }
}

// Fused dispatch: 1000 blocks, longest (fb2, 21 K-tiles) first for tail packing.
__global__ __launch_bounds__(256, 4)
void fbk_fused(const float* __restrict__ x,  const float* __restrict__ w0,
               const float* __restrict__ w1, const float* __restrict__ w2,
               float* __restrict__ out) {
    __shared__ unsigned short As[2][64][72];   // 18.4 KB
    __shared__ unsigned short Bs[2][64][72];   // 18.4 KB  (total 36.9 KB -> 4 blocks/CU)
    const int bid = blockIdx.x;
    if (bid < 328) {
        // fb2: w=64, s=16, d=256, P=82, K=1344, 4 n-tiles
        fbk_body<6, 4, 256, 82, 16, 1344>(x, w2, out + 43008, bid, As, Bs);
    } else if (bid < 662) {
        // fb1: w=32, s=8, d=128, P=167, K=672, 2 n-tiles
        fbk_body<5, 2, 128, 167, 8, 672>(x, w1, out + 21632, bid - 328, As, Bs);
    } else {
        // fb0: w=16, s=4, d=64, P=338, K=336, 1 n-tile
        fbk_body<4, 1, 64, 338, 4, 336>(x, w0, out, bid - 662, As, Bs);
    }
}

extern "C" void kernel_launch(void* const* d_in, const int* in_sizes, int n_in,
                              void* d_out, int out_size, void* d_ws, size_t ws_size,
                              hipStream_t stream) {
    const float* x  = (const float*)d_in[0];
    const float* w0 = (const float*)d_in[1];
    const float* w1 = (const float*)d_in[2];
    const float* w2 = (const float*)d_in[3];
    float* out = (float*)d_out;
    fbk_fused<<<dim3(1000), 256, 0, stream>>>(x, w0, w1, w2, out);
}

// Round 5
// 53.232 us; speedup vs baseline: 1.6078x; 1.0446x over previous
//
#include <hip/hip_runtime.h>

#define QDIM 21
#define NDIM 1368
#define OUTSTRIDE 64000

typedef __attribute__((ext_vector_type(4))) float f32x4;
typedef __attribute__((ext_vector_type(8))) short bf16x8s;
typedef __attribute__((ext_vector_type(4))) unsigned int u32x4;

typedef __attribute__((address_space(1))) const unsigned int* gas_p;
typedef __attribute__((address_space(3))) unsigned int* las_p;

static __device__ __forceinline__ void gload16(const float* g, char* l) {
    __builtin_amdgcn_global_load_lds((gas_p)(const void*)g, (las_p)(void*)l, 16, 0, 0);
}

// pack two f32 -> two bf16 (round-half-up): 3 VALU per pair
static __device__ __forceinline__ unsigned int pk2(float lo, float hi) {
    unsigned int a = __float_as_uint(lo) + 0x8000u;
    unsigned int b = __float_as_uint(hi) + 0x8000u;
    return __builtin_amdgcn_perm(b, a, 0x07060302);  // {b[31:16], a[31:16]}
}

static __device__ __forceinline__ bf16x8s pack8(float4 lo, float4 hi) {
    u32x4 p;
    p[0] = pk2(lo.x, lo.y);
    p[1] = pk2(lo.z, lo.w);
    p[2] = pk2(hi.x, hi.y);
    p[3] = pk2(hi.z, hi.w);
    return __builtin_bit_cast(bf16x8s, p);
}

// One 4-wave block computes C[0:64, n0:n0+64] for window position p.
// gload_lds ring pipeline: 3 stages x (A[64][32]f32 + B[64][32]f32) = 48 KB.
// Stage LDS row = 128 B = 8 segs of 16 B; XOR swizzle: LDS[r][s] holds global
// seg s^(r&7)  (loader fetches g=(l&7)^(l>>3); reader reads s=g^(r&7)).
// Per tile: waitcnt vmcnt(4); s_barrier; ds_read frags; pack; 4 MFMA;
// issue STAGE(t+2) into stage (t-1)%3 (reads of t-1 certified by this barrier).
template<int WLOG2, int NTX, int D, int P, int S, int K>
__device__ __forceinline__ void fbk_body(const float* __restrict__ x,
                                         const float* __restrict__ W,
                                         float* __restrict__ out, int bid,
                                         char* ldsraw) {
    constexpr int WWIN = 1 << WLOG2;
    constexpr int G = (K + 31) / 32;          // 42 / 21 / 11
    constexpr bool TAIL = (K % 32) != 0;      // fb0 only (K=336)
    constexpr int FMAXC = (K - 4) & ~3;       // aligned clamp for tail loads

    const int n0 = (bid % NTX) * 64;
    const int p  = bid / NTX;
    const int start = (p == P - 1) ? (NDIM - WWIN) : p * S;

    const int tid  = threadIdx.x;
    const int wid  = tid >> 6;
    const int lane = tid & 63;
    const int wm = (wid >> 1) * 32;
    const int wn = (wid & 1) * 32;
    const int lr = lane & 15;
    const int hi = lane >> 4;
    const int kb = hi * 8;

    // ---- staging lane constants (per-wave: 2 A-insts + 2 B-insts, 8 rows each)
    const int lrow = lane >> 3;                   // row within instruction
    const int g4   = ((lane & 7) ^ lrow) * 4;     // inverse-swizzled source col (floats)
    const int r0   = 16 * wid + lrow;             // global row of inst 0
    const float* xb0 = x + (size_t)r0 * QDIM * NDIM + start;
    const float* Wp  = W + (size_t)(p * D + n0) * K;
    const float* wb0 = Wp + (size_t)r0 * K;
    const float* wb1 = wb0 + (size_t)8 * K;
    const int wA = 2048 * wid;                    // wave's A byte offset in stage

    auto STAGE = [&](int t, int sbase) {
        int f = t * 32 + g4;
        if constexpr (TAIL) f = (f > FMAXC) ? FMAXC : f;   // garbage, zeroed at read
        int q = f >> WLOG2;
        int j = f & (WWIN - 1);
        const float* ga = xb0 + q * NDIM + j;
        char* la = ldsraw + sbase + wA;
        char* lb = ldsraw + sbase + 8192 + wA;
        gload16(ga, la);
        gload16(ga + (size_t)8 * QDIM * NDIM, la + 1024);
        gload16(wb0 + f, lb);
        gload16(wb1 + f, lb + 1024);
    };

    // ---- fragment-read constants (swizzled): (wm|wn)+16 keeps r&7 == lr&7
    const int x7 = lr & 7;
    const int c0 = ((hi * 2)     ^ x7) * 16;
    const int c1 = ((hi * 2 + 1) ^ x7) * 16;
    const int oA0 = (wm + lr) * 128;
    const int oA1 = (wm + 16 + lr) * 128;
    const int oB0 = 8192 + (wn + lr) * 128;
    const int oB1 = 8192 + (wn + 16 + lr) * 128;

    f32x4 acc[2][2] = {};

    STAGE(0, 0);
    STAGE(1, 16384);

    int cs = 0;   // byte base of current tile's stage
    #pragma unroll 1
    for (int t = 0; t < G; ++t) {
        if (t + 1 < G) { asm volatile("s_waitcnt vmcnt(4)" ::: "memory"); }
        else           { asm volatile("s_waitcnt vmcnt(0)" ::: "memory"); }
        __builtin_amdgcn_sched_barrier(0);
        __builtin_amdgcn_s_barrier();
        __builtin_amdgcn_sched_barrier(0);

        const char* sb = ldsraw + cs;
        float4 a00 = *(const float4*)(sb + oA0 + c0);
        float4 a01 = *(const float4*)(sb + oA0 + c1);
        float4 a10 = *(const float4*)(sb + oA1 + c0);
        float4 a11 = *(const float4*)(sb + oA1 + c1);
        float4 b00 = *(const float4*)(sb + oB0 + c0);
        float4 b01 = *(const float4*)(sb + oB0 + c1);
        float4 b10 = *(const float4*)(sb + oB1 + c0);
        float4 b11 = *(const float4*)(sb + oB1 + c1);

        if constexpr (TAIL) {
            if (t == G - 1 && kb >= (K & 31)) {     // fully-invalid fragments
                float4 z = make_float4(0.f, 0.f, 0.f, 0.f);
                a00 = z; a01 = z; a10 = z; a11 = z;
            }
        }

        bf16x8s A0 = pack8(a00, a01);
        bf16x8s A1 = pack8(a10, a11);
        bf16x8s B0 = pack8(b00, b01);
        bf16x8s B1 = pack8(b10, b11);

        acc[0][0] = __builtin_amdgcn_mfma_f32_16x16x32_bf16(A0, B0, acc[0][0], 0, 0, 0);
        acc[0][1] = __builtin_amdgcn_mfma_f32_16x16x32_bf16(A0, B1, acc[0][1], 0, 0, 0);
        acc[1][0] = __builtin_amdgcn_mfma_f32_16x16x32_bf16(A1, B0, acc[1][0], 0, 0, 0);
        acc[1][1] = __builtin_amdgcn_mfma_f32_16x16x32_bf16(A1, B1, acc[1][1], 0, 0, 0);

        __builtin_amdgcn_sched_barrier(0);
        if (t + 2 < G) {
            int pb = (cs == 0) ? 32768 : cs - 16384;   // stage (t+2)%3 == (t-1)%3
            STAGE(t + 2, pb);
        }
        cs = (cs == 32768) ? 0 : cs + 16384;
    }

    // epilogue: C/D layout col = lane&15, row = (lane>>4)*4 + r
    const int colbase = p * D + n0;
    #pragma unroll
    for (int mi = 0; mi < 2; ++mi) {
        #pragma unroll
        for (int ni = 0; ni < 2; ++ni) {
            int col = colbase + wn + ni * 16 + lr;
            int rbase = wm + mi * 16 + hi * 4;
            #pragma unroll
            for (int r = 0; r < 4; ++r) {
                out[(size_t)(rbase + r) * OUTSTRIDE + col] = acc[mi][ni][r];
            }
        }
    }
}

// Fused dispatch: 1000 blocks, longest (fb2, 42 tiles) first for tail packing.
__global__ __launch_bounds__(256, 3)
void fbk_fused(const float* __restrict__ x,  const float* __restrict__ w0,
               const float* __restrict__ w1, const float* __restrict__ w2,
               float* __restrict__ out) {
    __shared__ __align__(16) char ldsraw[49152];   // 3 stages x 16 KB -> 3 blocks/CU
    const int bid = blockIdx.x;
    if (bid < 328) {
        // fb2: w=64, s=16, d=256, P=82, K=1344, 4 n-tiles
        fbk_body<6, 4, 256, 82, 16, 1344>(x, w2, out + 43008, bid, ldsraw);
    } else if (bid < 662) {
        // fb1: w=32, s=8, d=128, P=167, K=672, 2 n-tiles
        fbk_body<5, 2, 128, 167, 8, 672>(x, w1, out + 21632, bid - 328, ldsraw);
    } else {
        // fb0: w=16, s=4, d=64, P=338, K=336, 1 n-tile
        fbk_body<4, 1, 64, 338, 4, 336>(x, w0, out, bid - 662, ldsraw);
    }
}

extern "C" void kernel_launch(void* const* d_in, const int* in_sizes, int n_in,
                              void* d_out, int out_size, void* d_ws, size_t ws_size,
                              hipStream_t stream) {
    const float* x  = (const float*)d_in[0];
    const float* w0 = (const float*)d_in[1];
    const float* w1 = (const float*)d_in[2];
    const float* w2 = (const float*)d_in[3];
    float* out = (float*)d_out;
    fbk_fused<<<dim3(1000), 256, 0, stream>>>(x, w0, w1, w2, out);
}